// Round 18
// baseline (22881.343 us; speedup 1.0000x reference)
//
#include <hip/hip_runtime.h>
#include <stdint.h>

typedef unsigned long long u64;
typedef u64 u64x2 __attribute__((ext_vector_type(2)));

#define VOCAB 128
#define RD 128
#define DM 1024
#define NFF 6
#define BATCH 64
#define TSTEPS 512

// ---------------------------------------------------------------------------
// ws layout (bytes): (identical to r15/r17, proven)
//   [0, 786432)       ffs  [L][half][q][c][2] u64:
//                     u64 idx = (((L*2+half)*8+q)*512 + c)*2 + s
//                     (word-pair q of column half*512+c)
//   [786432, +2048)   ebits [v][2] u64
//   [788480, +2048)   headb [v][2] u64
//   [790528, +512)    losses [64] double
// ---------------------------------------------------------------------------
#define OFF_EB    786432
#define OFF_HB    788480
#define OFF_LOSS  790528

// lgkm-only barrier: LDS h-writes drained; global weight loads (vmcnt)
// stay in flight across the barrier.
#define BARRIER()                                            \
    do {                                                     \
        asm volatile("s_waitcnt lgkmcnt(0)" ::: "memory");   \
        __builtin_amdgcn_s_barrier();                        \
    } while (0)

// Pack ff sign bits. bit b of word (L,w,j) = (ff[L][w*64+b][j] < 0)  (1 => -1)
__global__ void pack_ff(const float* __restrict__ ff, u64* __restrict__ ffs) {
    int wid  = blockIdx.x * (blockDim.x >> 6) + (threadIdx.x >> 6); // 0..1535
    int lane = threadIdx.x & 63;
    int jt = wid & 15;
    int w  = (wid >> 4) & 15;  // word 0..15
    int L  = wid >> 8;         // layer
    int j  = jt * 64 + lane;   // column
    const float* src = ff + ((size_t)(L * DM) + w * 64) * DM + j;
    u64 word = 0;
#pragma unroll
    for (int b = 0; b < 64; ++b) {
        float v = src[(size_t)b * DM];
        word |= (u64)(v < 0.0f) << b;
    }
    int half = j >> 9, c = j & 511, q = w >> 1, s = w & 1;
    ffs[((((L * 2 + half) * 8 + q) * 512 + c) << 1) + s] = word;
}

// Pack embed rows and head columns (tiny).
__global__ void pack_small(const float* __restrict__ emb, const float* __restrict__ head,
                           u64* __restrict__ eb, u64* __restrict__ hb) {
    int tid = threadIdx.x; // 0..255
    if (tid < 128) {
        int v = tid;
        for (int wd = 0; wd < 2; ++wd) {
            u64 word = 0;
            for (int l = 0; l < 64; ++l)
                word |= (u64)(emb[v * RD + wd * 64 + l] < 0.0f) << l;
            eb[v * 2 + wd] = word;
        }
    } else {
        int v = tid - 128;
        for (int wd = 0; wd < 2; ++wd) {
            u64 word = 0;
            for (int l = 0; l < 64; ++l)
                word |= (u64)(head[(wd * 64 + l) * VOCAB + v] < 0.0f) << l;
            hb[v * 2 + wd] = word;
        }
    }
}

// One streamed layer L (literal): consume p[] and, PER WORD-PAIR, re-issue
// that pair's load for layer PFL (in flight for a full layer before its next
// consume, crossing lgkm-only barriers). q-order is skewed per wave (qq =
// (q+wv)&7) so the 16 barrier-locked waves don't burst the same pipe at the
// same instant; accumulation is order-independent.
#define SLAYER(L, PFL)                                                     \
    do {                                                                   \
        const ulonglong2* hp_ = (const ulonglong2*)hx[(L) & 1];            \
        int acc_ = 0;                                                      \
        _Pragma("unroll")                                                  \
        for (int q_ = 0; q_ < 8; ++q_) {                                   \
            const int qq_ = (q_ + wv) & 7;                                 \
            ulonglong2 hv_ = hp_[qq_]; /* broadcast ds_read_b128 */        \
            acc_ += __popcll(hv_.x ^ p[2 * qq_]) +                         \
                    __popcll(hv_.y ^ p[2 * qq_ + 1]);                      \
            u64x2 v_ = wsrc[(((PFL) * 16 + (half << 3) + qq_) << 9) + cc]; \
            p[2 * qq_] = v_.x; p[2 * qq_ + 1] = v_.y;                      \
        }                                                                  \
        u64 m_ = __ballot(acc_ >= cthr[L]);                                \
        if (lane == 0) hx[((L) + 1) & 1][wv] = m_;                         \
        BARRIER();                                                         \
    } while (0)

// Main recurrent kernel: one block (one CU) per batch row, 1024 threads,
// 4 waves/SIMD with waves_per_eu(4,4) -> 128-reg/wave budget (16x128 = full
// RF). Layer 5 LDS-resident (128 KB); layer 4 register-resident (32 VGPRs);
// layers 0-3 streamed with interleaved consume/reissue. Ask ~94 <= 128.
__global__ void
__attribute__((amdgpu_flat_work_group_size(1024, 1024), amdgpu_waves_per_eu(4, 4)))
brnn_main(const int* __restrict__ tokens,
          const float* __restrict__ initial_lat,
          const float* __restrict__ thr_lat,
          const u64* __restrict__ ffs,
          const u64* __restrict__ eb,
          const u64* __restrict__ hb,
          double* __restrict__ losses)
{
    const int b    = blockIdx.x;
    const int tid  = threadIdx.x;
    const int lane = tid & 63;
    const int wv   = tid >> 6;   // 0..15
    const int half = tid >> 9;   // 0 or 1
    const int cc   = tid & 511;  // column within half

    __shared__ __align__(16) u64 wlds[8][1024][2]; // layer 5: 128 KB
    __shared__ __align__(16) u64 hx[2][16];
    __shared__ u64 hbL[2 * VOCAB];

    const u64x2* wsrc = (const u64x2*)ffs;

    // --- one-time: stage layer 5 into LDS (coalesced) ---
#pragma unroll
    for (int q = 0; q < 8; ++q) {
        u64x2 v = wsrc[((5 * 16 + (half << 3) + q) << 9) + cc];
        wlds[q][tid][0] = v.x;
        wlds[q][tid][1] = v.y;
    }

    // --- layer 4 register-resident: this thread's column, 16 u64 = 32 VGPR ---
    u64 fr[16];
#pragma unroll
    for (int q = 0; q < 8; ++q) {
        u64x2 v = wsrc[((4 * 16 + (half << 3) + q) << 9) + cc];
        fr[2 * q] = v.x; fr[2 * q + 1] = v.y;
    }

    // thresholds -> popcount cutoffs:  bit(-1) <=> pre < thr  <=>  acc >= cthr
    int cthr[NFF];
#pragma unroll
    for (int L = 0; L < NFF; ++L) {
        int th = (int)rintf(thr_lat[L * DM + tid]); // round-half-even == jnp.round
        cthr[L] = ((DM - th) >> 1) + 1;
    }

    if (tid < 2 * VOCAB) hbL[tid] = hb[tid];

    // --- init h = sign(initial_lat) into hx[0] ---
    {
        u64 m = __ballot(initial_lat[tid] < 0.0f);
        if (lane == 0) hx[0][wv] = m;
    }

    // streaming buffer: this thread's column of the current streamed layer
    u64 p[16];
#pragma unroll
    for (int q = 0; q < 8; ++q) {
        u64x2 v = wsrc[((0 * 16 + (half << 3) + q) << 9) + cc];
        p[2 * q] = v.x; p[2 * q + 1] = v.y;
    }
    __syncthreads(); // one-time full barrier (wlds + hx + hbL visible)

    const int* toks = tokens + b * TSTEPS;
    double lacc = 0.0;

    for (int t = 0; t < TSTEPS; ++t) {
        const int tok = toks[t]; // uniform -> scalar load
        u64 enew = 0;
        if (wv == 0 && lane < 2) enew = eb[tok * 2 + lane]; // prefetch for splice

        SLAYER(0, 1);
        SLAYER(1, 2);
        SLAYER(2, 3);
        SLAYER(3, 0);   // re-issues layer 0 for step t+1 (covered by L4+L5+head)

        // --- layer 4 from registers: h in hx[0] -> hx[1] ---
        {
            const ulonglong2* hp = (const ulonglong2*)hx[0];
            int acc = 0;
#pragma unroll
            for (int q = 0; q < 8; ++q) {
                const int qq = (q + wv) & 7;
                ulonglong2 hv = hp[qq]; // broadcast
                acc += __popcll(hv.x ^ fr[2 * qq]) + __popcll(hv.y ^ fr[2 * qq + 1]);
            }
            u64 m = __ballot(acc >= cthr[4]);
            if (lane == 0) hx[1][wv] = m;
            BARRIER();
        }

        // --- layer 5 from LDS: h in hx[1] -> hx[0] ---
        {
            const ulonglong2* hp = (const ulonglong2*)hx[1];
            int acc = 0;
#pragma unroll
            for (int q = 0; q < 8; ++q) {
                const int qq = (q + wv) & 7;
                ulonglong2 hv = hp[qq];                        // broadcast
                ulonglong2 w  = *(const ulonglong2*)wlds[qq][tid];
                acc += __popcll(hv.x ^ w.x) + __popcll(hv.y ^ w.y);
            }
            u64 m = __ballot(acc >= cthr[5]);
            if (lane == 0) hx[0][wv] = m;
            BARRIER();
        }

        // --- head + log-softmax + loss + embed splice (wave 0); h5 in hx[0] ---
        if (wv == 0) {
            u64 ra = hx[0][14], rb = hx[0][15];
            u64 h0a = hbL[lane * 2 + 0],        h0b = hbL[lane * 2 + 1];
            u64 h1a = hbL[(lane + 64) * 2 + 0], h1b = hbL[(lane + 64) * 2 + 1];
            int d0 = 128 - 2 * (__popcll(ra ^ h0a) + __popcll(rb ^ h0b));
            int d1 = 128 - 2 * (__popcll(ra ^ h1a) + __popcll(rb ^ h1b));
            float l0 = (float)d0 * (1.0f / 16.0f);
            float l1 = (float)d1 * (1.0f / 16.0f);
            float mx = fmaxf(l0, l1);
#pragma unroll
            for (int sh = 32; sh >= 1; sh >>= 1) mx = fmaxf(mx, __shfl_xor(mx, sh));
            float se = __expf(l0 - mx) + __expf(l1 - mx);
#pragma unroll
            for (int sh = 32; sh >= 1; sh >>= 1) se += __shfl_xor(se, sh);
            int   tl   = tok & 63;
            float la   = __shfl(l0, tl);
            float lb   = __shfl(l1, tl);
            float ltok = (tok >> 6) ? lb : la;
            lacc += (double)(mx + __logf(se) - ltok);
            // splice x_new read-part = sign(embed[tok]) into words 14,15
            if (lane < 2) hx[0][14 + lane] = enew;
        }
        BARRIER();
    }

    if (tid == 0) losses[b] = lacc;
}

__global__ void reduce_loss(const double* __restrict__ losses, float* __restrict__ out) {
    int lane = threadIdx.x; // 64 threads, 1 wave
    double v = losses[lane];
#pragma unroll
    for (int sh = 32; sh >= 1; sh >>= 1) v += __shfl_down(v, sh);
    if (lane == 0) out[0] = (float)(v * (1.0 / ((double)BATCH * (double)TSTEPS)));
}

extern "C" void kernel_launch(void* const* d_in, const int* in_sizes, int n_in,
                              void* d_out, int out_size, void* d_ws, size_t ws_size,
                              hipStream_t stream) {
    const int*   tokens  = (const int*)d_in[0];   // (64, 512) int32
    const float* initial = (const float*)d_in[1]; // (1024,)
    const float* embed   = (const float*)d_in[2]; // (128, 128)
    const float* ff      = (const float*)d_in[3]; // (6, 1024, 1024)
    const float* head    = (const float*)d_in[4]; // (128, 128)
    const float* thrl    = (const float*)d_in[5]; // (6, 1024)

    char* ws = (char*)d_ws;
    u64*    ffs    = (u64*)ws;                 // 786432 B
    u64*    eb     = (u64*)(ws + OFF_EB);      // 2048 B
    u64*    hb     = (u64*)(ws + OFF_HB);      // 2048 B
    double* losses = (double*)(ws + OFF_LOSS); // 512 B

    pack_ff<<<384, 256, 0, stream>>>(ff, ffs);
    pack_small<<<1, 256, 0, stream>>>(embed, head, eb, hb);
    brnn_main<<<BATCH, 1024, 0, stream>>>(tokens, initial, thrl, ffs, eb, hb, losses);
    reduce_loss<<<1, 64, 0, stream>>>(losses, (float*)d_out);
}

// Round 19
// 6930.343 us; speedup vs baseline: 3.3016x; 3.3016x over previous
//
#include <hip/hip_runtime.h>
#include <stdint.h>

typedef unsigned long long u64;

#define VOCAB 128
#define RD 128
#define DM 1024
#define NFF 6
#define BATCH 64
#define TSTEPS 512
#define THR 512

// ---------------------------------------------------------------------------
// ws layout (bytes):
//   [0, 786432)       ffs: swizzled DMA layout.
//                     u64 idx = L*16384 + (j>>9)*8192 + (j&511)*16
//                               + ((q ^ (j&7))<<1) + s      (w = 2q+s)
//                     -> linear global_load_lds delivery puts pair q of
//                        column c at LDS byte c*128 + (q^(c&7))*16
//                        (bank-conflict-free swizzled reads).
//   [786432, +2048)   ebits [v][2] u64
//   [788480, +2048)   headb [v][2] u64
//   [790528, +512)    losses [64] double
// ---------------------------------------------------------------------------
#define OFF_EB    786432
#define OFF_HB    788480
#define OFF_LOSS  790528

typedef const __attribute__((address_space(1))) void* gas1_t;
typedef __attribute__((address_space(3))) void*       las3_t;

// Pack ff sign bits into the swizzled DMA layout.
// bit b of word (L,w,j) = (ff[L][w*64+b][j] < 0)  (1 => -1)
__global__ void pack_ff(const float* __restrict__ ff, u64* __restrict__ ffs) {
    int wid  = blockIdx.x * (blockDim.x >> 6) + (threadIdx.x >> 6); // 0..1535
    int lane = threadIdx.x & 63;
    int jt = wid & 15;
    int w  = (wid >> 4) & 15;  // word 0..15
    int L  = wid >> 8;         // layer
    int j  = jt * 64 + lane;   // column
    const float* src = ff + ((size_t)(L * DM) + w * 64) * DM + j;
    u64 word = 0;
#pragma unroll
    for (int b = 0; b < 64; ++b) {
        float v = src[(size_t)b * DM];
        word |= (u64)(v < 0.0f) << b;
    }
    int q = w >> 1, s = w & 1;
    size_t dst = (size_t)L * 16384 + (size_t)(j >> 9) * 8192
               + (size_t)(j & 511) * 16 + ((q ^ (j & 7)) << 1) + s;
    ffs[dst] = word;
}

// Pack embed rows and head columns (tiny).
__global__ void pack_small(const float* __restrict__ emb, const float* __restrict__ head,
                           u64* __restrict__ eb, u64* __restrict__ hb) {
    int tid = threadIdx.x; // 0..255
    if (tid < 128) {
        int v = tid;
        for (int wd = 0; wd < 2; ++wd) {
            u64 word = 0;
            for (int l = 0; l < 64; ++l)
                word |= (u64)(emb[v * RD + wd * 64 + l] < 0.0f) << l;
            eb[v * 2 + wd] = word;
        }
    } else {
        int v = tid - 128;
        for (int wd = 0; wd < 2; ++wd) {
            u64 word = 0;
            for (int l = 0; l < 64; ++l)
                word |= (u64)(head[(wd * 64 + l) * VOCAB + v] < 0.0f) << l;
            hb[v * 2 + wd] = word;
        }
    }
}

// Issue the 64 KB half-layer (L,H) into staging buffer NB via global_load_lds:
// 8 dwordx4 instructions per wave, wave-uniform LDS base + lane*16 (HW rule).
// Zero VGPR cost -> 64 KB in flight per CU.
#define ISSUE(L, H, NB)                                                        \
    do {                                                                       \
        const u64* gp_ = ffs + ((L) * 16384 + (H) * 8192 + (wv << 10) + (lane << 1)); \
        u64* lp_ = sbuf + ((NB) * 8192 + (wv << 10));                          \
        _Pragma("unroll")                                                      \
        for (int k_ = 0; k_ < 8; ++k_) {                                       \
            __builtin_amdgcn_global_load_lds((gas1_t)(gp_ + (k_ << 7)),        \
                                             (las3_t)(lp_ + (k_ << 7)), 16, 0, 0); \
        }                                                                      \
    } while (0)

// Compute half-layer (L,H) from staging buffer NB: thread tid owns column
// H*512+tid. Weight pair q at swizzled LDS offset tid*16 + ((q^(tid&7))<<1)
// -> lanes spread across all 8 bank-slots (conflict-free-equivalent).
#define CSTAGE(L, H, NB)                                                       \
    do {                                                                       \
        const ulonglong2* hp_ = (const ulonglong2*)hx[(L) & 1];                \
        const u64* wb_ = sbuf + ((NB) * 8192 + tid * 16);                      \
        int acc_ = 0;                                                          \
        _Pragma("unroll")                                                      \
        for (int q_ = 0; q_ < 8; ++q_) {                                       \
            ulonglong2 hv_ = hp_[q_]; /* broadcast ds_read_b128 */             \
            ulonglong2 wq_ = *(const ulonglong2*)(wb_ + ((q_ ^ (tid & 7)) << 1)); \
            acc_ += __popcll(hv_.x ^ wq_.x) + __popcll(hv_.y ^ wq_.y);         \
        }                                                                      \
        u64 m_ = __ballot(acc_ >= cthr[L][H]);                                 \
        if (lane == 0) hx[((L) + 1) & 1][(H) * 8 + wv] = m_;                   \
    } while (0)

// Stage barrier: drain MY wave's DMA (next buffer) + LDS ops, then barrier.
// After it, the next staging buffer is fully written (all waves drained).
#define SBAR()                                                                  \
    do {                                                                        \
        asm volatile("s_waitcnt vmcnt(0) lgkmcnt(0)" ::: "memory");             \
        __builtin_amdgcn_s_barrier();                                           \
    } while (0)

// lgkm-only barrier (for head/splice phase)
#define BARRIER()                                                               \
    do {                                                                        \
        asm volatile("s_waitcnt lgkmcnt(0)" ::: "memory");                      \
        __builtin_amdgcn_s_barrier();                                           \
    } while (0)

// Main recurrent kernel: one block (one CU) per batch row, 512 threads.
// All 6 layers stream L2 -> LDS via global_load_lds through two 64 KB
// staging buffers (12 half-layer stages/step); stage s+1's DMA overlaps
// stage s's compute. ~48 VGPRs vs 128 grant: spill impossible.
__global__ void __launch_bounds__(THR)
brnn_main(const int* __restrict__ tokens,
          const float* __restrict__ initial_lat,
          const float* __restrict__ thr_lat,
          const u64* __restrict__ ffs,
          const u64* __restrict__ eb,
          const u64* __restrict__ hb,
          double* __restrict__ losses)
{
    const int b    = blockIdx.x;
    const int tid  = threadIdx.x;
    const int lane = tid & 63;
    const int wv   = tid >> 6;   // 0..7

    __shared__ __align__(16) u64 sbuf[2 * 8192];  // 2 x 64 KB staging
    __shared__ __align__(16) u64 hx[2][16];
    __shared__ u64 hbL[2 * VOCAB];

    if (tid < 2 * VOCAB) hbL[tid] = hb[tid];

    // thresholds: thread handles col H*512+tid of each layer
    int cthr[NFF][2];
#pragma unroll
    for (int L = 0; L < NFF; ++L)
#pragma unroll
        for (int h2 = 0; h2 < 2; ++h2) {
            int th = (int)rintf(thr_lat[L * DM + h2 * 512 + tid]); // round-half-even
            cthr[L][h2] = ((DM - th) >> 1) + 1;
        }

    // init h = sign(initial_lat) into hx[0] (two ballots: words wv, 8+wv)
    {
        u64 m0 = __ballot(initial_lat[tid] < 0.0f);
        u64 m1 = __ballot(initial_lat[512 + tid] < 0.0f);
        if (lane == 0) { hx[0][wv] = m0; hx[0][8 + wv] = m1; }
    }

    // prologue: stage (0,0) into buffer 0
    ISSUE(0, 0, 0);
    asm volatile("s_waitcnt vmcnt(0)" ::: "memory");
    __syncthreads();

    const int* toks = tokens + b * TSTEPS;
    double lacc = 0.0;

    for (int t = 0; t < TSTEPS; ++t) {
        const int tok = toks[t]; // uniform -> scalar load
        u64 enew = 0;
        if (wv == 0 && lane < 2) enew = eb[tok * 2 + lane]; // prefetch for splice

        // --- 12 half-layer stages, 1-deep DMA pipeline ---
        ISSUE(0, 1, 1); CSTAGE(0, 0, 0); SBAR();
        ISSUE(1, 0, 0); CSTAGE(0, 1, 1); SBAR();
        ISSUE(1, 1, 1); CSTAGE(1, 0, 0); SBAR();
        ISSUE(2, 0, 0); CSTAGE(1, 1, 1); SBAR();
        ISSUE(2, 1, 1); CSTAGE(2, 0, 0); SBAR();
        ISSUE(3, 0, 0); CSTAGE(2, 1, 1); SBAR();
        ISSUE(3, 1, 1); CSTAGE(3, 0, 0); SBAR();
        ISSUE(4, 0, 0); CSTAGE(3, 1, 1); SBAR();
        ISSUE(4, 1, 1); CSTAGE(4, 0, 0); SBAR();
        ISSUE(5, 0, 0); CSTAGE(4, 1, 1); SBAR();
        ISSUE(5, 1, 1); CSTAGE(5, 0, 0); SBAR();
        ISSUE(0, 0, 0); CSTAGE(5, 1, 1); SBAR();   // prefetch next step's (0,0)

        // --- head + log-softmax + loss + embed splice (wave 0); h5 in hx[0] ---
        if (wv == 0) {
            u64 ra = hx[0][14], rb = hx[0][15];
            u64 h0a = hbL[lane * 2 + 0],        h0b = hbL[lane * 2 + 1];
            u64 h1a = hbL[(lane + 64) * 2 + 0], h1b = hbL[(lane + 64) * 2 + 1];
            int d0 = 128 - 2 * (__popcll(ra ^ h0a) + __popcll(rb ^ h0b));
            int d1 = 128 - 2 * (__popcll(ra ^ h1a) + __popcll(rb ^ h1b));
            float l0 = (float)d0 * (1.0f / 16.0f);
            float l1 = (float)d1 * (1.0f / 16.0f);
            float mx = fmaxf(l0, l1);
#pragma unroll
            for (int sh = 32; sh >= 1; sh >>= 1) mx = fmaxf(mx, __shfl_xor(mx, sh));
            float se = __expf(l0 - mx) + __expf(l1 - mx);
#pragma unroll
            for (int sh = 32; sh >= 1; sh >>= 1) se += __shfl_xor(se, sh);
            int   tl   = tok & 63;
            float la   = __shfl(l0, tl);
            float lb   = __shfl(l1, tl);
            float ltok = (tok >> 6) ? lb : la;
            lacc += (double)(mx + __logf(se) - ltok);
            // splice x_new read-part = sign(embed[tok]) into words 14,15
            if (lane < 2) hx[0][14 + lane] = enew;
        }
        BARRIER();
    }

    if (tid == 0) losses[b] = lacc;
}

__global__ void reduce_loss(const double* __restrict__ losses, float* __restrict__ out) {
    int lane = threadIdx.x; // 64 threads, 1 wave
    double v = losses[lane];
#pragma unroll
    for (int sh = 32; sh >= 1; sh >>= 1) v += __shfl_down(v, sh);
    if (lane == 0) out[0] = (float)(v * (1.0 / ((double)BATCH * (double)TSTEPS)));
}

extern "C" void kernel_launch(void* const* d_in, const int* in_sizes, int n_in,
                              void* d_out, int out_size, void* d_ws, size_t ws_size,
                              hipStream_t stream) {
    const int*   tokens  = (const int*)d_in[0];   // (64, 512) int32
    const float* initial = (const float*)d_in[1]; // (1024,)
    const float* embed   = (const float*)d_in[2]; // (128, 128)
    const float* ff      = (const float*)d_in[3]; // (6, 1024, 1024)
    const float* head    = (const float*)d_in[4]; // (128, 128)
    const float* thrl    = (const float*)d_in[5]; // (6, 1024)

    char* ws = (char*)d_ws;
    u64*    ffs    = (u64*)ws;                 // 786432 B
    u64*    eb     = (u64*)(ws + OFF_EB);      // 2048 B
    u64*    hb     = (u64*)(ws + OFF_HB);      // 2048 B
    double* losses = (double*)(ws + OFF_LOSS); // 512 B

    pack_ff<<<384, 256, 0, stream>>>(ff, ffs);
    pack_small<<<1, 256, 0, stream>>>(embed, head, eb, hb);
    brnn_main<<<BATCH, THR, 0, stream>>>(tokens, initial, thrl, ffs, eb, hb, losses);
    reduce_loss<<<1, 64, 0, stream>>>(losses, (float*)d_out);
}

// Round 20
// 6049.634 us; speedup vs baseline: 3.7823x; 1.1456x over previous
//
#include <hip/hip_runtime.h>
#include <stdint.h>

typedef unsigned long long u64;

#define VOCAB 128
#define RD 128
#define DM 1024
#define NFF 6
#define BATCH 64
#define TSTEPS 512
#define THR 512

// ---------------------------------------------------------------------------
// ws layout (bytes): ffs in the PROVEN r15/r17 layout:
//   [0, 786432)       ffs  [L][half][q][c][2] u64:
//                     u64 idx = (((L*2+half)*8+q)*512 + c)*2 + s
//                     Linear DMA of one 64 KB half-layer delivers LDS
//                     sbuf[q][c][2]: pair q of col c at byte q*8192+c*16
//                     -> ds_read_b128 lane stride 16 B = conflict-free.
//   [786432, +2048)   ebits [v][2] u64
//   [788480, +2048)   headb [v][2] u64
//   [790528, +512)    losses [64] double
// ---------------------------------------------------------------------------
#define OFF_EB    786432
#define OFF_HB    788480
#define OFF_LOSS  790528

typedef const __attribute__((address_space(1))) void* gas1_t;
typedef __attribute__((address_space(3))) void*       las3_t;

// Pack ff sign bits. bit b of word (L,w,j) = (ff[L][w*64+b][j] < 0)  (1 => -1)
__global__ void pack_ff(const float* __restrict__ ff, u64* __restrict__ ffs) {
    int wid  = blockIdx.x * (blockDim.x >> 6) + (threadIdx.x >> 6); // 0..1535
    int lane = threadIdx.x & 63;
    int jt = wid & 15;
    int w  = (wid >> 4) & 15;  // word 0..15
    int L  = wid >> 8;         // layer
    int j  = jt * 64 + lane;   // column
    const float* src = ff + ((size_t)(L * DM) + w * 64) * DM + j;
    u64 word = 0;
#pragma unroll
    for (int b = 0; b < 64; ++b) {
        float v = src[(size_t)b * DM];
        word |= (u64)(v < 0.0f) << b;
    }
    int half = j >> 9, c = j & 511, q = w >> 1, s = w & 1;
    ffs[((((L * 2 + half) * 8 + q) * 512 + c) << 1) + s] = word;
}

// Pack embed rows and head columns (tiny).
__global__ void pack_small(const float* __restrict__ emb, const float* __restrict__ head,
                           u64* __restrict__ eb, u64* __restrict__ hb) {
    int tid = threadIdx.x; // 0..255
    if (tid < 128) {
        int v = tid;
        for (int wd = 0; wd < 2; ++wd) {
            u64 word = 0;
            for (int l = 0; l < 64; ++l)
                word |= (u64)(emb[v * RD + wd * 64 + l] < 0.0f) << l;
            eb[v * 2 + wd] = word;
        }
    } else {
        int v = tid - 128;
        for (int wd = 0; wd < 2; ++wd) {
            u64 word = 0;
            for (int l = 0; l < 64; ++l)
                word |= (u64)(head[(wd * 64 + l) * VOCAB + v] < 0.0f) << l;
            hb[v * 2 + wd] = word;
        }
    }
}

// Issue the 64 KB half-layer (L,H) into staging buffer NB via global_load_lds:
// instruction (wv,k) copies 1 KB linearly; LDS base wave-uniform, lane*16
// applied by HW on both sides. Zero VGPR cost -> 64 KB in flight per CU.
#define ISSUE(L, H, NB)                                                        \
    do {                                                                       \
        const u64* gp_ = ffs + (((L) * 2 + (H)) * 8192) + (wv << 10) + (lane << 1); \
        u64* lp_ = sbuf + ((NB) * 8192 + (wv << 10));                          \
        _Pragma("unroll")                                                      \
        for (int k_ = 0; k_ < 8; ++k_) {                                       \
            __builtin_amdgcn_global_load_lds((gas1_t)(gp_ + (k_ << 7)),        \
                                             (las3_t)(lp_ + (k_ << 7)), 16, 0, 0); \
        }                                                                      \
    } while (0)

// Compute half-layer (L,H) from staging buffer NB: thread tid owns column
// H*512+tid. Weight pair q at u64 idx NB*8192 + q*1024 + tid*2
// (byte q*8192 + tid*16): 16-B lane stride -> conflict-free b128 reads.
#define CSTAGE(L, H, NB)                                                       \
    do {                                                                       \
        const ulonglong2* hp_ = (const ulonglong2*)hx[(L) & 1];                \
        const u64* wb_ = sbuf + ((NB) * 8192 + (tid << 1));                    \
        int acc_ = 0;                                                          \
        _Pragma("unroll")                                                      \
        for (int q_ = 0; q_ < 8; ++q_) {                                       \
            ulonglong2 hv_ = hp_[q_]; /* broadcast ds_read_b128 */             \
            ulonglong2 wq_ = *(const ulonglong2*)(wb_ + (q_ << 10));           \
            acc_ += __popcll(hv_.x ^ wq_.x) + __popcll(hv_.y ^ wq_.y);         \
        }                                                                      \
        u64 m_ = __ballot(acc_ >= cthr[L][H]);                                 \
        if (lane == 0) hx[((L) + 1) & 1][(H) * 8 + wv] = m_;                   \
    } while (0)

// Stage barrier: drain DMA (next buffer) + LDS ops, then barrier.
#define SBAR()                                                                  \
    do {                                                                        \
        asm volatile("s_waitcnt vmcnt(0) lgkmcnt(0)" ::: "memory");             \
        __builtin_amdgcn_s_barrier();                                           \
    } while (0)

// lgkm-only barrier (for head/splice phase)
#define BARRIER()                                                               \
    do {                                                                        \
        asm volatile("s_waitcnt lgkmcnt(0)" ::: "memory");                      \
        __builtin_amdgcn_s_barrier();                                           \
    } while (0)

// Main recurrent kernel: one block (one CU) per batch row, 512 threads.
// All 6 layers stream L2 -> LDS via global_load_lds through two 64 KB
// staging buffers (12 half-layer stages/step); stage s+1's DMA overlaps
// stage s's compute. ~48 VGPRs vs 128 grant: spill impossible.
__global__ void __launch_bounds__(THR)
brnn_main(const int* __restrict__ tokens,
          const float* __restrict__ initial_lat,
          const float* __restrict__ thr_lat,
          const u64* __restrict__ ffs,
          const u64* __restrict__ eb,
          const u64* __restrict__ hb,
          double* __restrict__ losses)
{
    const int b    = blockIdx.x;
    const int tid  = threadIdx.x;
    const int lane = tid & 63;
    const int wv   = tid >> 6;   // 0..7

    __shared__ __align__(16) u64 sbuf[2 * 8192];  // 2 x 64 KB staging
    __shared__ __align__(16) u64 hx[2][16];
    __shared__ u64 hbL[2 * VOCAB];

    if (tid < 2 * VOCAB) hbL[tid] = hb[tid];

    // thresholds: thread handles col H*512+tid of each layer
    int cthr[NFF][2];
#pragma unroll
    for (int L = 0; L < NFF; ++L)
#pragma unroll
        for (int h2 = 0; h2 < 2; ++h2) {
            int th = (int)rintf(thr_lat[L * DM + h2 * 512 + tid]); // round-half-even
            cthr[L][h2] = ((DM - th) >> 1) + 1;
        }

    // init h = sign(initial_lat) into hx[0] (two ballots: words wv, 8+wv)
    {
        u64 m0 = __ballot(initial_lat[tid] < 0.0f);
        u64 m1 = __ballot(initial_lat[512 + tid] < 0.0f);
        if (lane == 0) { hx[0][wv] = m0; hx[0][8 + wv] = m1; }
    }

    // prologue: stage (0,0) into buffer 0
    ISSUE(0, 0, 0);
    asm volatile("s_waitcnt vmcnt(0)" ::: "memory");
    __syncthreads();

    const int* toks = tokens + b * TSTEPS;
    double lacc = 0.0;

    for (int t = 0; t < TSTEPS; ++t) {
        const int tok = toks[t]; // uniform -> scalar load
        u64 enew = 0;
        if (wv == 0 && lane < 2) enew = eb[tok * 2 + lane]; // prefetch for splice

        // --- 12 half-layer stages, 1-deep DMA pipeline ---
        ISSUE(0, 1, 1); CSTAGE(0, 0, 0); SBAR();
        ISSUE(1, 0, 0); CSTAGE(0, 1, 1); SBAR();
        ISSUE(1, 1, 1); CSTAGE(1, 0, 0); SBAR();
        ISSUE(2, 0, 0); CSTAGE(1, 1, 1); SBAR();
        ISSUE(2, 1, 1); CSTAGE(2, 0, 0); SBAR();
        ISSUE(3, 0, 0); CSTAGE(2, 1, 1); SBAR();
        ISSUE(3, 1, 1); CSTAGE(3, 0, 0); SBAR();
        ISSUE(4, 0, 0); CSTAGE(3, 1, 1); SBAR();
        ISSUE(4, 1, 1); CSTAGE(4, 0, 0); SBAR();
        ISSUE(5, 0, 0); CSTAGE(4, 1, 1); SBAR();
        ISSUE(5, 1, 1); CSTAGE(5, 0, 0); SBAR();
        ISSUE(0, 0, 0); CSTAGE(5, 1, 1); SBAR();   // prefetch next step's (0,0)

        // --- head + log-softmax + loss + embed splice (wave 0); h5 in hx[0] ---
        if (wv == 0) {
            u64 ra = hx[0][14], rb = hx[0][15];
            u64 h0a = hbL[lane * 2 + 0],        h0b = hbL[lane * 2 + 1];
            u64 h1a = hbL[(lane + 64) * 2 + 0], h1b = hbL[(lane + 64) * 2 + 1];
            int d0 = 128 - 2 * (__popcll(ra ^ h0a) + __popcll(rb ^ h0b));
            int d1 = 128 - 2 * (__popcll(ra ^ h1a) + __popcll(rb ^ h1b));
            float l0 = (float)d0 * (1.0f / 16.0f);
            float l1 = (float)d1 * (1.0f / 16.0f);
            float mx = fmaxf(l0, l1);
#pragma unroll
            for (int sh = 32; sh >= 1; sh >>= 1) mx = fmaxf(mx, __shfl_xor(mx, sh));
            float se = __expf(l0 - mx) + __expf(l1 - mx);
#pragma unroll
            for (int sh = 32; sh >= 1; sh >>= 1) se += __shfl_xor(se, sh);
            int   tl   = tok & 63;
            float la   = __shfl(l0, tl);
            float lb   = __shfl(l1, tl);
            float ltok = (tok >> 6) ? lb : la;
            lacc += (double)(mx + __logf(se) - ltok);
            // splice x_new read-part = sign(embed[tok]) into words 14,15
            if (lane < 2) hx[0][14 + lane] = enew;
        }
        BARRIER();
    }

    if (tid == 0) losses[b] = lacc;
}

__global__ void reduce_loss(const double* __restrict__ losses, float* __restrict__ out) {
    int lane = threadIdx.x; // 64 threads, 1 wave
    double v = losses[lane];
#pragma unroll
    for (int sh = 32; sh >= 1; sh >>= 1) v += __shfl_down(v, sh);
    if (lane == 0) out[0] = (float)(v * (1.0 / ((double)BATCH * (double)TSTEPS)));
}

extern "C" void kernel_launch(void* const* d_in, const int* in_sizes, int n_in,
                              void* d_out, int out_size, void* d_ws, size_t ws_size,
                              hipStream_t stream) {
    const int*   tokens  = (const int*)d_in[0];   // (64, 512) int32
    const float* initial = (const float*)d_in[1]; // (1024,)
    const float* embed   = (const float*)d_in[2]; // (128, 128)
    const float* ff      = (const float*)d_in[3]; // (6, 1024, 1024)
    const float* head    = (const float*)d_in[4]; // (128, 128)
    const float* thrl    = (const float*)d_in[5]; // (6, 1024)

    char* ws = (char*)d_ws;
    u64*    ffs    = (u64*)ws;                 // 786432 B
    u64*    eb     = (u64*)(ws + OFF_EB);      // 2048 B
    u64*    hb     = (u64*)(ws + OFF_HB);      // 2048 B
    double* losses = (double*)(ws + OFF_LOSS); // 512 B

    pack_ff<<<384, 256, 0, stream>>>(ff, ffs);
    pack_small<<<1, 256, 0, stream>>>(embed, head, eb, hb);
    brnn_main<<<BATCH, THR, 0, stream>>>(tokens, initial, thrl, ffs, eb, hb, losses);
    reduce_loss<<<1, 64, 0, stream>>>(losses, (float*)d_out);
}